// Round 1
// baseline (427.965 us; speedup 1.0000x reference)
//
#include <hip/hip_runtime.h>
#include <hip/hip_bf16.h>
#include <stdint.h>

// Swin window-attention block, fully fused per window.
// Grid: 1536 blocks (one per (batch,window)), 512 threads (8 waves).
// LDS: Bx[64][200] bf16 (X -> Q -> O), Bp[64][200] bf16 (Px -> K),
//      Vt[192][72] bf16 (V transposed), Ps[8][16][68] f32 (per-wave P tile).

#define NTOK 64
#define CDIM 192
#define NHEAD 6
#define NWIN 192
#define LDX 200   // bf16 stride for token-major tiles (192 + 8 pad)
#define LDV 72    // bf16 stride for Vt (64 + 8 pad)
#define LDP 68    // f32 stride for Ps (64 + 4 pad)

typedef short bf16x8 __attribute__((ext_vector_type(8)));
typedef short short4v __attribute__((ext_vector_type(4)));
typedef float f32x4 __attribute__((ext_vector_type(4)));

static __device__ __forceinline__ short f2bf(float f) {
    uint32_t u = __float_as_uint(f);
    u += 0x7fffu + ((u >> 16) & 1u);   // RNE
    return (short)(u >> 16);
}

// ---- prep: weights f32->bf16, bias table gather ----
__global__ void prep_kernel(const float* __restrict__ wq, const float* __restrict__ wkv,
                            const float* __restrict__ wp, const int* __restrict__ rpi,
                            const float* __restrict__ rpb,
                            short* __restrict__ wq_b, short* __restrict__ wkv_b,
                            short* __restrict__ wp_b, float* __restrict__ bias)
{
    int gid = blockIdx.x * 256 + threadIdx.x;   // 0..36863 (float4 units)
    const float4* src; short4v* dst; int idx;
    if (gid < 9216)       { src = (const float4*)wq;  dst = (short4v*)wq_b;  idx = gid; }
    else if (gid < 27648) { src = (const float4*)wkv; dst = (short4v*)wkv_b; idx = gid - 9216; }
    else                  { src = (const float4*)wp;  dst = (short4v*)wp_b;  idx = gid - 27648; }
    float4 v = src[idx];
    short4v o; o[0]=f2bf(v.x); o[1]=f2bf(v.y); o[2]=f2bf(v.z); o[3]=f2bf(v.w);
    dst[idx] = o;
    if (gid < 24576) {  // bias[h][n][m] = rpb_table[rpi[n][m]][h]
        int h = gid >> 12, nm = gid & 4095;
        bias[gid] = rpb[rpi[nm] * NHEAD + h];
    }
}

__global__ void __launch_bounds__(512, 2)
swin_fused(const float* __restrict__ x, const float* __restrict__ px,
           const float* __restrict__ mask, const float* __restrict__ biasT,
           const short* __restrict__ wq_b, const short* __restrict__ wkv_b,
           const short* __restrict__ wp_b,
           const float* __restrict__ bq, const float* __restrict__ bkv,
           const float* __restrict__ bp, float* __restrict__ out)
{
    extern __shared__ char smem[];
    short* Bx = (short*)smem;                 // [64][LDX]
    short* Bp = Bx + 64 * LDX;                // [64][LDX]
    short* Vt = Bp + 64 * LDX;                // [192][LDV]
    float* Ps = (float*)(Vt + 192 * LDV);     // [8][16][LDP]

    const int tid = threadIdx.x;
    const int wv  = tid >> 6;    // wave 0..7
    const int ln  = tid & 63;
    const int lc  = ln & 15;     // MFMA lane col (M-row of A / N-col of B,D)
    const int lg  = ln >> 4;     // lane group 0..3 (K-chunk / D-row group)
    const int b_  = blockIdx.x;
    const int win = b_ % NWIN;

    const f32x4 zf = {0.f, 0.f, 0.f, 0.f};

    // ---------- stage x, px -> LDS bf16 ----------
    {
        const float4* xs = (const float4*)(x  + (size_t)b_ * (NTOK * CDIM));
        const float4* ps = (const float4*)(px + (size_t)b_ * (NTOK * CDIM));
        #pragma unroll
        for (int i = 0; i < 6; ++i) {
            int f = tid + 512 * i;           // 0..3071 float4s
            int row = f / 48, col = (f - row * 48) * 4;
            float4 v = xs[f];
            float4 w = ps[f];
            short4v a; a[0]=f2bf(v.x); a[1]=f2bf(v.y); a[2]=f2bf(v.z); a[3]=f2bf(v.w);
            short4v b; b[0]=f2bf(w.x); b[1]=f2bf(w.y); b[2]=f2bf(w.z); b[3]=f2bf(w.w);
            *(short4v*)(&Bx[row * LDX + col]) = a;
            *(short4v*)(&Bp[row * LDX + col]) = b;
        }
    }
    __syncthreads();

    // ---------- KV GEMM: Bp(64x192) @ wkv^T -> K (waves 0-3) / V (waves 4-7) ----------
    {
        const int cb = wv * 48;              // output-channel base (0..383)
        f32x4 acc[4][3];
        #pragma unroll
        for (int mt = 0; mt < 4; ++mt)
            #pragma unroll
            for (int ct = 0; ct < 3; ++ct) acc[mt][ct] = zf;
        #pragma unroll
        for (int kk = 0; kk < 6; ++kk) {
            const int k0 = kk * 32 + lg * 8;
            bf16x8 bfr[3];
            #pragma unroll
            for (int ct = 0; ct < 3; ++ct)
                bfr[ct] = *(const bf16x8*)(&wkv_b[(cb + ct * 16 + lc) * CDIM + k0]);
            #pragma unroll
            for (int mt = 0; mt < 4; ++mt) {
                bf16x8 afr = *(const bf16x8*)(&Bp[(mt * 16 + lc) * LDX + k0]);
                #pragma unroll
                for (int ct = 0; ct < 3; ++ct)
                    acc[mt][ct] = __builtin_amdgcn_mfma_f32_16x16x32_bf16(afr, bfr[ct], acc[mt][ct], 0, 0, 0);
            }
        }
        __syncthreads();   // all reads of Bp done -> safe to overwrite as Ks
        if (wv < 4) {      // K channels cb..cb+47 -> Bp row-major
            #pragma unroll
            for (int ct = 0; ct < 3; ++ct) {
                const int ch = cb + ct * 16 + lc;
                const float bb = bkv[ch];
                #pragma unroll
                for (int mt = 0; mt < 4; ++mt)
                    #pragma unroll
                    for (int j = 0; j < 4; ++j)
                        Bp[(mt * 16 + lg * 4 + j) * LDX + ch] = f2bf(acc[mt][ct][j] + bb);
            }
        } else {           // V channels -> Vt transposed [ch][token]
            const int vb = cb - 192;
            #pragma unroll
            for (int ct = 0; ct < 3; ++ct) {
                const int vch = vb + ct * 16 + lc;
                const float bb = bkv[192 + vch];
                #pragma unroll
                for (int mt = 0; mt < 4; ++mt)
                    #pragma unroll
                    for (int j = 0; j < 4; ++j)
                        Vt[vch * LDV + (mt * 16 + lg * 4 + j)] = f2bf(acc[mt][ct][j] + bb);
            }
        }
    }
    __syncthreads();

    // ---------- Q GEMM: Bx(64x192) @ wq^T -> Qs (aliases Bx) ----------
    {
        const int mt = wv >> 1;              // row tile
        const int cb = (wv & 1) * 96;        // col half
        f32x4 acc[6];
        #pragma unroll
        for (int ct = 0; ct < 6; ++ct) acc[ct] = zf;
        #pragma unroll
        for (int kk = 0; kk < 6; ++kk) {
            const int k0 = kk * 32 + lg * 8;
            bf16x8 afr = *(const bf16x8*)(&Bx[(mt * 16 + lc) * LDX + k0]);
            #pragma unroll
            for (int ct = 0; ct < 6; ++ct) {
                bf16x8 bfr = *(const bf16x8*)(&wq_b[(cb + ct * 16 + lc) * CDIM + k0]);
                acc[ct] = __builtin_amdgcn_mfma_f32_16x16x32_bf16(afr, bfr, acc[ct], 0, 0, 0);
            }
        }
        __syncthreads();   // all reads of Bx done -> safe to overwrite as Qs
        #pragma unroll
        for (int ct = 0; ct < 6; ++ct) {
            const int ch = cb + ct * 16 + lc;
            const float bb = bq[ch];
            #pragma unroll
            for (int j = 0; j < 4; ++j)
                Bx[(mt * 16 + lg * 4 + j) * LDX + ch] = f2bf(acc[ct][j] + bb);
        }
    }
    __syncthreads();

    // ---------- attention: wave owns rows [rt,rt+16) x heads [hb,hb+3) ----------
    f32x4 oacc[6];
    #pragma unroll
    for (int i = 0; i < 6; ++i) oacc[i] = zf;
    const int rt = (wv >> 1) * 16;
    const int hb = (wv & 1) * 3;
    float maskv[4][4];
    {
        const float* mrow = mask + (size_t)win * 4096;
        #pragma unroll
        for (int t = 0; t < 4; ++t)
            #pragma unroll
            for (int j = 0; j < 4; ++j)
                maskv[t][j] = mrow[(rt + lg * 4 + j) * 64 + t * 16 + lc];
    }
    const float scale = 0.17677669529663687f;   // 32^-0.5
    float* pw = Ps + wv * (16 * LDP);

    for (int hh = 0; hh < 3; ++hh) {
        const int h = hb + hh;
        // S = Q_h @ K_h^T  (16x64, K=32)
        bf16x8 aQ = *(const bf16x8*)(&Bx[(rt + lc) * LDX + h * 32 + lg * 8]);
        f32x4 s[4];
        #pragma unroll
        for (int t = 0; t < 4; ++t) {
            bf16x8 bK = *(const bf16x8*)(&Bp[(t * 16 + lc) * LDX + h * 32 + lg * 8]);
            s[t] = __builtin_amdgcn_mfma_f32_16x16x32_bf16(aQ, bK, zf, 0, 0, 0);
        }
        const float* brow = biasT + h * 4096;
        float pr[4][4];
        #pragma unroll
        for (int j = 0; j < 4; ++j) {
            const int rbase = (rt + lg * 4 + j) * 64 + lc;
            float v0 = s[0][j] * scale + brow[rbase     ] + maskv[0][j];
            float v1 = s[1][j] * scale + brow[rbase + 16] + maskv[1][j];
            float v2 = s[2][j] * scale + brow[rbase + 32] + maskv[2][j];
            float v3 = s[3][j] * scale + brow[rbase + 48] + maskv[3][j];
            float mx = fmaxf(fmaxf(v0, v1), fmaxf(v2, v3));
            #pragma unroll
            for (int d = 1; d < 16; d <<= 1) mx = fmaxf(mx, __shfl_xor(mx, d, 64));
            float e0 = __expf(v0 - mx), e1 = __expf(v1 - mx);
            float e2 = __expf(v2 - mx), e3 = __expf(v3 - mx);
            float sm = (e0 + e1) + (e2 + e3);
            #pragma unroll
            for (int d = 1; d < 16; d <<= 1) sm += __shfl_xor(sm, d, 64);
            float inv = 1.0f / sm;
            pr[0][j] = e0 * inv; pr[1][j] = e1 * inv;
            pr[2][j] = e2 * inv; pr[3][j] = e3 * inv;
        }
        // wave-private P tile: fence prior PV reads before overwrite (rule #18)
        asm volatile("s_waitcnt lgkmcnt(0)" ::: "memory");
        __builtin_amdgcn_sched_barrier(0);
        #pragma unroll
        for (int t = 0; t < 4; ++t)
            #pragma unroll
            for (int j = 0; j < 4; ++j)
                pw[(lg * 4 + j) * LDP + t * 16 + lc] = pr[t][j];
        asm volatile("s_waitcnt lgkmcnt(0)" ::: "memory");
        __builtin_amdgcn_sched_barrier(0);
        // O_h += P @ V_h  (16x32, K=64)
        #pragma unroll
        for (int ks = 0; ks < 2; ++ks) {
            const float* prd = pw + lc * LDP + ks * 32 + lg * 8;
            float4 lo = *(const float4*)prd;
            float4 hi = *(const float4*)(prd + 4);
            bf16x8 pf;
            pf[0]=f2bf(lo.x); pf[1]=f2bf(lo.y); pf[2]=f2bf(lo.z); pf[3]=f2bf(lo.w);
            pf[4]=f2bf(hi.x); pf[5]=f2bf(hi.y); pf[6]=f2bf(hi.z); pf[7]=f2bf(hi.w);
            #pragma unroll
            for (int t2 = 0; t2 < 2; ++t2) {
                bf16x8 vf = *(const bf16x8*)(&Vt[(h * 32 + t2 * 16 + lc) * LDV + ks * 32 + lg * 8]);
                oacc[hh * 2 + t2] = __builtin_amdgcn_mfma_f32_16x16x32_bf16(pf, vf, oacc[hh * 2 + t2], 0, 0, 0);
            }
        }
    }
    __syncthreads();   // all waves done reading Qs(Bx)
    // O -> Bx (bf16, row-major)
    #pragma unroll
    for (int hh = 0; hh < 3; ++hh)
        #pragma unroll
        for (int t2 = 0; t2 < 2; ++t2) {
            const int col = (hb + hh) * 32 + t2 * 16 + lc;
            #pragma unroll
            for (int j = 0; j < 4; ++j)
                Bx[(rt + lg * 4 + j) * LDX + col] = f2bf(oacc[hh * 2 + t2][j]);
        }
    __syncthreads();

    // ---------- out projection: Bx(64x192) @ wp^T + bp -> global ----------
    {
        const int mt = wv >> 1;
        const int cb = (wv & 1) * 96;
        f32x4 acc[6];
        #pragma unroll
        for (int ct = 0; ct < 6; ++ct) acc[ct] = zf;
        #pragma unroll
        for (int kk = 0; kk < 6; ++kk) {
            const int k0 = kk * 32 + lg * 8;
            bf16x8 afr = *(const bf16x8*)(&Bx[(mt * 16 + lc) * LDX + k0]);
            #pragma unroll
            for (int ct = 0; ct < 6; ++ct) {
                bf16x8 bfr = *(const bf16x8*)(&wp_b[(cb + ct * 16 + lc) * CDIM + k0]);
                acc[ct] = __builtin_amdgcn_mfma_f32_16x16x32_bf16(afr, bfr, acc[ct], 0, 0, 0);
            }
        }
        float* orow = out + (size_t)b_ * (NTOK * CDIM);
        #pragma unroll
        for (int ct = 0; ct < 6; ++ct) {
            const int ch = cb + ct * 16 + lc;
            const float bb = bp[ch];
            #pragma unroll
            for (int j = 0; j < 4; ++j)
                orow[(mt * 16 + lg * 4 + j) * CDIM + ch] = acc[ct][j] + bb;
        }
    }
}

extern "C" void kernel_launch(void* const* d_in, const int* in_sizes, int n_in,
                              void* d_out, int out_size, void* d_ws, size_t ws_size,
                              hipStream_t stream) {
    const float* x    = (const float*)d_in[0];
    const float* px   = (const float*)d_in[1];
    const float* mask = (const float*)d_in[2];
    const int*   rpi  = (const int*)d_in[3];
    const float* rpb  = (const float*)d_in[4];
    const float* wq   = (const float*)d_in[5];
    const float* bq   = (const float*)d_in[6];
    const float* wkv  = (const float*)d_in[7];
    const float* bkv  = (const float*)d_in[8];
    const float* wp   = (const float*)d_in[9];
    const float* bp   = (const float*)d_in[10];
    float* out = (float*)d_out;

    char* ws = (char*)d_ws;
    short* wq_b  = (short*)ws;                          // 73728 B
    short* wkv_b = (short*)(ws + 73728);                // 147456 B
    short* wp_b  = (short*)(ws + 73728 + 147456);       // 73728 B
    float* bias  = (float*)(ws + 73728 + 147456 + 73728); // 98304 B

    prep_kernel<<<144, 256, 0, stream>>>(wq, wkv, wp, rpi, rpb, wq_b, wkv_b, wp_b, bias);

    const int lds_bytes = (64 * LDX + 64 * LDX + 192 * LDV) * 2 + 8 * 16 * LDP * 4; // 113664
    hipFuncSetAttribute((const void*)swin_fused, hipFuncAttributeMaxDynamicSharedMemorySize, lds_bytes);
    swin_fused<<<1536, 512, lds_bytes, stream>>>(x, px, mask, bias, wq_b, wkv_b, wp_b,
                                                 bq, bkv, bp, out);
}

// Round 2
// 333.732 us; speedup vs baseline: 1.2824x; 1.2824x over previous
//
#include <hip/hip_runtime.h>
#include <hip/hip_bf16.h>
#include <stdint.h>

// Swin window-attention block, fully fused per window.
// Grid: 1536 blocks (one per (batch,window)), 512 threads (8 waves).
// LDS (78.8 KiB -> 2 blocks/CU): Bx[64][200] bf16 (X -> Q -> O),
// Bp[64][200] bf16 (Px -> K), Vt[192][72] bf16 (V transposed).
// P never touches LDS: swapped QK^T (S^T = mfma(K,Q)) keeps each q-row
// lane-local; P->A-frag relayout is a 4-lane shfl permutation.

#define NTOK 64
#define CDIM 192
#define NHEAD 6
#define NWIN 192
#define LDX 200   // bf16 stride for token-major tiles (192 + 8 pad)
#define LDV 72    // bf16 stride for Vt (64 + 8 pad)

typedef short bf16x8 __attribute__((ext_vector_type(8)));
typedef short short4v __attribute__((ext_vector_type(4)));
typedef float f32x4 __attribute__((ext_vector_type(4)));
typedef int   i32x4 __attribute__((ext_vector_type(4)));

static __device__ __forceinline__ short f2bf(float f) {
    uint32_t u = __float_as_uint(f);
    u += 0x7fffu + ((u >> 16) & 1u);   // RNE
    return (short)(u >> 16);
}
static __device__ __forceinline__ int pack2bf(float lo, float hi) {
    return ((int)(unsigned short)f2bf(hi) << 16) | (int)(unsigned short)f2bf(lo);
}

// ---- prep: weights f32->bf16, bias table gather ----
__global__ void prep_kernel(const float* __restrict__ wq, const float* __restrict__ wkv,
                            const float* __restrict__ wp, const int* __restrict__ rpi,
                            const float* __restrict__ rpb,
                            short* __restrict__ wq_b, short* __restrict__ wkv_b,
                            short* __restrict__ wp_b, float* __restrict__ bias)
{
    int gid = blockIdx.x * 256 + threadIdx.x;   // 0..36863 (float4 units)
    const float4* src; short4v* dst; int idx;
    if (gid < 9216)       { src = (const float4*)wq;  dst = (short4v*)wq_b;  idx = gid; }
    else if (gid < 27648) { src = (const float4*)wkv; dst = (short4v*)wkv_b; idx = gid - 9216; }
    else                  { src = (const float4*)wp;  dst = (short4v*)wp_b;  idx = gid - 27648; }
    float4 v = src[idx];
    short4v o; o[0]=f2bf(v.x); o[1]=f2bf(v.y); o[2]=f2bf(v.z); o[3]=f2bf(v.w);
    dst[idx] = o;
    if (gid < 24576) {  // bias[h][n][m] = rpb_table[rpi[n][m]][h]
        int h = gid >> 12, nm = gid & 4095;
        bias[gid] = rpb[rpi[nm] * NHEAD + h];
    }
}

__global__ void __launch_bounds__(512, 4)
swin_fused(const float* __restrict__ x, const float* __restrict__ px,
           const float* __restrict__ mask, const float* __restrict__ biasT,
           const short* __restrict__ wq_b, const short* __restrict__ wkv_b,
           const short* __restrict__ wp_b,
           const float* __restrict__ bq, const float* __restrict__ bkv,
           const float* __restrict__ bp, float* __restrict__ out)
{
    extern __shared__ char smem[];
    short* Bx = (short*)smem;                 // [64][LDX]
    short* Bp = Bx + 64 * LDX;                // [64][LDX]
    short* Vt = Bp + 64 * LDX;                // [192][LDV]

    const int tid = threadIdx.x;
    const int wv  = tid >> 6;    // wave 0..7
    const int ln  = tid & 63;
    const int lc  = ln & 15;     // MFMA lane col
    const int lg  = ln >> 4;     // lane group 0..3
    const int b_  = blockIdx.x;
    const int win = b_ % NWIN;

    const f32x4 zf = {0.f, 0.f, 0.f, 0.f};

    // ---------- stage x, px -> LDS bf16 ----------
    {
        const float4* xs = (const float4*)(x  + (size_t)b_ * (NTOK * CDIM));
        const float4* ps = (const float4*)(px + (size_t)b_ * (NTOK * CDIM));
        #pragma unroll
        for (int i = 0; i < 6; ++i) {
            int f = tid + 512 * i;           // 0..3071 float4s
            int row = f / 48, col = (f - row * 48) * 4;
            float4 v = xs[f];
            float4 w = ps[f];
            short4v a; a[0]=f2bf(v.x); a[1]=f2bf(v.y); a[2]=f2bf(v.z); a[3]=f2bf(v.w);
            short4v b; b[0]=f2bf(w.x); b[1]=f2bf(w.y); b[2]=f2bf(w.z); b[3]=f2bf(w.w);
            *(short4v*)(&Bx[row * LDX + col]) = a;
            *(short4v*)(&Bp[row * LDX + col]) = b;
        }
    }
    __syncthreads();

    // ---------- KV GEMM: Bp(64x192) @ wkv^T -> K (waves 0-3) / V (waves 4-7) ----------
    {
        const int cb = wv * 48;              // output-channel base (0..383)
        f32x4 acc[4][3];
        #pragma unroll
        for (int mt = 0; mt < 4; ++mt)
            #pragma unroll
            for (int ct = 0; ct < 3; ++ct) acc[mt][ct] = zf;
        #pragma unroll
        for (int kk = 0; kk < 6; ++kk) {
            const int k0 = kk * 32 + lg * 8;
            bf16x8 bfr[3];
            #pragma unroll
            for (int ct = 0; ct < 3; ++ct)
                bfr[ct] = *(const bf16x8*)(&wkv_b[(cb + ct * 16 + lc) * CDIM + k0]);
            #pragma unroll
            for (int mt = 0; mt < 4; ++mt) {
                bf16x8 afr = *(const bf16x8*)(&Bp[(mt * 16 + lc) * LDX + k0]);
                #pragma unroll
                for (int ct = 0; ct < 3; ++ct)
                    acc[mt][ct] = __builtin_amdgcn_mfma_f32_16x16x32_bf16(afr, bfr[ct], acc[mt][ct], 0, 0, 0);
            }
        }
        __syncthreads();   // all reads of Bp done -> safe to overwrite as Ks
        if (wv < 4) {      // K channels cb..cb+47 -> Bp row-major
            #pragma unroll
            for (int ct = 0; ct < 3; ++ct) {
                const int ch = cb + ct * 16 + lc;
                const float bb = bkv[ch];
                #pragma unroll
                for (int mt = 0; mt < 4; ++mt)
                    #pragma unroll
                    for (int j = 0; j < 4; ++j)
                        Bp[(mt * 16 + lg * 4 + j) * LDX + ch] = f2bf(acc[mt][ct][j] + bb);
            }
        } else {           // V channels -> Vt transposed [ch][token], b64 writes
            const int vb = cb - 192;
            #pragma unroll
            for (int ct = 0; ct < 3; ++ct) {
                const int vch = vb + ct * 16 + lc;
                const float bb = bkv[192 + vch];
                #pragma unroll
                for (int mt = 0; mt < 4; ++mt) {
                    short4v o;
                    #pragma unroll
                    for (int j = 0; j < 4; ++j) o[j] = f2bf(acc[mt][ct][j] + bb);
                    *(short4v*)(&Vt[vch * LDV + mt * 16 + lg * 4]) = o;
                }
            }
        }
    }
    __syncthreads();

    // ---------- Q GEMM: Bx(64x192) @ wq^T -> Qs (aliases Bx) ----------
    {
        const int mt = wv >> 1;              // row tile
        const int cb = (wv & 1) * 96;        // col half
        f32x4 acc[6];
        #pragma unroll
        for (int ct = 0; ct < 6; ++ct) acc[ct] = zf;
        #pragma unroll
        for (int kk = 0; kk < 6; ++kk) {
            const int k0 = kk * 32 + lg * 8;
            bf16x8 afr = *(const bf16x8*)(&Bx[(mt * 16 + lc) * LDX + k0]);
            #pragma unroll
            for (int ct = 0; ct < 6; ++ct) {
                bf16x8 bfr = *(const bf16x8*)(&wq_b[(cb + ct * 16 + lc) * CDIM + k0]);
                acc[ct] = __builtin_amdgcn_mfma_f32_16x16x32_bf16(afr, bfr, acc[ct], 0, 0, 0);
            }
        }
        __syncthreads();   // all reads of Bx done -> safe to overwrite as Qs
        #pragma unroll
        for (int ct = 0; ct < 6; ++ct) {
            const int ch = cb + ct * 16 + lc;
            const float bb = bq[ch];
            #pragma unroll
            for (int j = 0; j < 4; ++j)
                Bx[(mt * 16 + lg * 4 + j) * LDX + ch] = f2bf(acc[ct][j] + bb);
        }
    }
    __syncthreads();

    // ---------- attention: wave owns q-rows [rt,rt+16) x heads [hb,hb+3) ----------
    // Swapped QK^T: st[t] = mfma(K_t, Q) -> lane (lg,lc) holds
    // S[q=rt+lc][k=t*16+lg*4+j]. Softmax reduces over lg bits (xor 16,32).
    f32x4 oacc[6];
    #pragma unroll
    for (int i = 0; i < 6; ++i) oacc[i] = zf;
    const int rt = (wv >> 1) * 16;
    const int hb = (wv & 1) * 3;
    const int hi = lg >> 1;              // tile-select bit for P relayout
    const int sA = ((lg & 1) * 2) * 16 + lc;      // shfl source lanes
    const int sB = sA + 16;
    float4 mask4[4];
    {
        const float* mrow = mask + (size_t)win * 4096 + (rt + lc) * 64 + lg * 4;
        #pragma unroll
        for (int t = 0; t < 4; ++t) mask4[t] = *(const float4*)(mrow + t * 16);
    }
    const float scale = 0.17677669529663687f;   // 32^-0.5

    for (int hh = 0; hh < 3; ++hh) {
        const int h = hb + hh;
        bf16x8 bQ = *(const bf16x8*)(&Bx[(rt + lc) * LDX + h * 32 + lg * 8]);
        f32x4 st[4];
        #pragma unroll
        for (int t = 0; t < 4; ++t) {
            bf16x8 aK = *(const bf16x8*)(&Bp[(t * 16 + lc) * LDX + h * 32 + lg * 8]);
            st[t] = __builtin_amdgcn_mfma_f32_16x16x32_bf16(aK, bQ, zf, 0, 0, 0);
        }
        const float* brow = biasT + h * 4096 + (rt + lc) * 64 + lg * 4;
        float p[4][4];
        float mx = -3.0e38f;
        #pragma unroll
        for (int t = 0; t < 4; ++t) {
            float4 b4 = *(const float4*)(brow + t * 16);
            p[t][0] = st[t][0] * scale + b4.x + mask4[t].x;
            p[t][1] = st[t][1] * scale + b4.y + mask4[t].y;
            p[t][2] = st[t][2] * scale + b4.z + mask4[t].z;
            p[t][3] = st[t][3] * scale + b4.w + mask4[t].w;
            mx = fmaxf(mx, fmaxf(fmaxf(p[t][0], p[t][1]), fmaxf(p[t][2], p[t][3])));
        }
        mx = fmaxf(mx, __shfl_xor(mx, 16, 64));
        mx = fmaxf(mx, __shfl_xor(mx, 32, 64));
        float sm = 0.f;
        #pragma unroll
        for (int t = 0; t < 4; ++t) {
            p[t][0] = __expf(p[t][0] - mx);
            p[t][1] = __expf(p[t][1] - mx);
            p[t][2] = __expf(p[t][2] - mx);
            p[t][3] = __expf(p[t][3] - mx);
            sm += (p[t][0] + p[t][1]) + (p[t][2] + p[t][3]);
        }
        sm += __shfl_xor(sm, 16, 64);
        sm += __shfl_xor(sm, 32, 64);
        const float inv = 1.0f / sm;
        int pk[4][2];
        #pragma unroll
        for (int t = 0; t < 4; ++t) {
            pk[t][0] = pack2bf(p[t][0] * inv, p[t][1] * inv);
            pk[t][1] = pack2bf(p[t][2] * inv, p[t][3] * inv);
        }
        // P relayout: dest lane (lg,lc) A-frag reg r <- pk[2ks+hi][r&1] of lane a+(r>>1)
        #pragma unroll
        for (int ks = 0; ks < 2; ++ks) {
            const int t0 = ks * 2, t1 = ks * 2 + 1;
            int w0 = hi ? __shfl(pk[t1][0], sA, 64) : 0;
            int w0b = !hi ? __shfl(pk[t0][0], sA, 64) : 0;
            // NOTE: __shfl must be executed by all lanes; compute both then select.
            w0 = hi ? __shfl(pk[t1][0], sA, 64) : __shfl(pk[t0][0], sA, 64);
            (void)w0b;
            int u0a = __shfl(pk[t0][0], sA, 64), u0b = __shfl(pk[t1][0], sA, 64);
            int u1a = __shfl(pk[t0][1], sA, 64), u1b = __shfl(pk[t1][1], sA, 64);
            int u2a = __shfl(pk[t0][0], sB, 64), u2b = __shfl(pk[t1][0], sB, 64);
            int u3a = __shfl(pk[t0][1], sB, 64), u3b = __shfl(pk[t1][1], sB, 64);
            i32x4 wi;
            wi[0] = hi ? u0b : u0a;
            wi[1] = hi ? u1b : u1a;
            wi[2] = hi ? u2b : u2a;
            wi[3] = hi ? u3b : u3a;
            bf16x8 pf = __builtin_bit_cast(bf16x8, wi);
            #pragma unroll
            for (int t2 = 0; t2 < 2; ++t2) {
                bf16x8 vf = *(const bf16x8*)(&Vt[(h * 32 + t2 * 16 + lc) * LDV + ks * 32 + lg * 8]);
                oacc[hh * 2 + t2] = __builtin_amdgcn_mfma_f32_16x16x32_bf16(pf, vf, oacc[hh * 2 + t2], 0, 0, 0);
            }
        }
    }
    __syncthreads();   // all waves done reading Qs(Bx)
    // O -> Bx (bf16, row-major); D-layout: row = rt + lg*4+j, col = ch
    #pragma unroll
    for (int hh = 0; hh < 3; ++hh)
        #pragma unroll
        for (int t2 = 0; t2 < 2; ++t2) {
            const int col = (hb + hh) * 32 + t2 * 16 + lc;
            #pragma unroll
            for (int j = 0; j < 4; ++j)
                Bx[(rt + lg * 4 + j) * LDX + col] = f2bf(oacc[hh * 2 + t2][j]);
        }
    __syncthreads();

    // ---------- out projection: Bx(64x192) @ wp^T + bp -> global ----------
    {
        const int mt = wv >> 1;
        const int cb = (wv & 1) * 96;
        f32x4 acc[6];
        #pragma unroll
        for (int ct = 0; ct < 6; ++ct) acc[ct] = zf;
        #pragma unroll
        for (int kk = 0; kk < 6; ++kk) {
            const int k0 = kk * 32 + lg * 8;
            bf16x8 afr = *(const bf16x8*)(&Bx[(mt * 16 + lc) * LDX + k0]);
            #pragma unroll
            for (int ct = 0; ct < 6; ++ct) {
                bf16x8 bfr = *(const bf16x8*)(&wp_b[(cb + ct * 16 + lc) * CDIM + k0]);
                acc[ct] = __builtin_amdgcn_mfma_f32_16x16x32_bf16(afr, bfr, acc[ct], 0, 0, 0);
            }
        }
        float* orow = out + (size_t)b_ * (NTOK * CDIM);
        #pragma unroll
        for (int ct = 0; ct < 6; ++ct) {
            const int ch = cb + ct * 16 + lc;
            const float bb = bp[ch];
            #pragma unroll
            for (int j = 0; j < 4; ++j)
                orow[(mt * 16 + lg * 4 + j) * CDIM + ch] = acc[ct][j] + bb;
        }
    }
}

extern "C" void kernel_launch(void* const* d_in, const int* in_sizes, int n_in,
                              void* d_out, int out_size, void* d_ws, size_t ws_size,
                              hipStream_t stream) {
    const float* x    = (const float*)d_in[0];
    const float* px   = (const float*)d_in[1];
    const float* mask = (const float*)d_in[2];
    const int*   rpi  = (const int*)d_in[3];
    const float* rpb  = (const float*)d_in[4];
    const float* wq   = (const float*)d_in[5];
    const float* bq   = (const float*)d_in[6];
    const float* wkv  = (const float*)d_in[7];
    const float* bkv  = (const float*)d_in[8];
    const float* wp   = (const float*)d_in[9];
    const float* bp   = (const float*)d_in[10];
    float* out = (float*)d_out;

    char* ws = (char*)d_ws;
    short* wq_b  = (short*)ws;                          // 73728 B
    short* wkv_b = (short*)(ws + 73728);                // 147456 B
    short* wp_b  = (short*)(ws + 73728 + 147456);       // 73728 B
    float* bias  = (float*)(ws + 73728 + 147456 + 73728); // 98304 B

    prep_kernel<<<144, 256, 0, stream>>>(wq, wkv, wp, rpi, rpb, wq_b, wkv_b, wp_b, bias);

    const int lds_bytes = (64 * LDX + 64 * LDX + 192 * LDV) * 2;   // 78848
    hipFuncSetAttribute((const void*)swin_fused, hipFuncAttributeMaxDynamicSharedMemorySize, lds_bytes);
    swin_fused<<<1536, 512, lds_bytes, stream>>>(x, px, mask, bias, wq_b, wkv_b, wp_b,
                                                 bq, bkv, bp, out);
}